// Round 1
// baseline (1115.632 us; speedup 1.0000x reference)
//
#include <hip/hip_runtime.h>
#include <cstdio>
#include <cstdint>

typedef unsigned int u32;
typedef unsigned short u16;
typedef short bf16x8 __attribute__((ext_vector_type(8)));   // 8 bf16 = 4 VGPRs (MFMA A/B operand)
typedef float f32x4 __attribute__((ext_vector_type(4)));    // MFMA C/D operand

#define NPTS 262144
#define CDIM 256
#define KCLS 20

// ---- workspace layout (bytes) ----
// [0, 134217728)                : h bf16 [N][256] row-major
// [134217728, +163840)          : Wt bf16 [320][256]  (rows 0-255: w1^T, 256-275: ws^T, 276-319: 0)
// then fp32: sum_h[256] sumsq_h[256] Aarr[256] Barr[256] scal[16]
#define OFF_WT   ((size_t)134217728)
#define OFF_STAT (OFF_WT + (size_t)163840)
#define WS_NEED  (OFF_STAT + (size_t)4160)

__device__ __forceinline__ u16 bf16rne(float x) {
    u32 u = __float_as_uint(x);
    u32 r = u + 0x7FFFu + ((u >> 16) & 1u);   // round-to-nearest-even
    return (u16)(r >> 16);
}
__device__ __forceinline__ float bf2f(u16 b) {
    return __uint_as_float(((u32)b) << 16);
}

// ---------------------------------------------------------------------------
// kernel 0: build Wt[320][256] bf16 = transposed [w1 | ws | zero-pad]
// Wt[n][k] = n<256 ? w1[k][n] : (n<276 ? ws[k][n-256] : 0)
// ---------------------------------------------------------------------------
__global__ void k_prep(const float* __restrict__ w1, const float* __restrict__ wsm,
                       u16* __restrict__ Wt) {
    int n = blockIdx.x;      // 0..319
    int k = threadIdx.x;     // 0..255
    float v = 0.f;
    if (n < 256) v = w1[k * 256 + n];
    else if (n < 256 + KCLS) v = wsm[k * KCLS + (n - 256)];
    Wt[n * 256 + k] = bf16rne(v);
}

// ---------------------------------------------------------------------------
// kernel 1: h = feat @ w1 (+b1) via bf16 MFMA; fused logits = feat @ ws (+bs)
//   -> seg NLL (in-register logsumexp), per-channel sum/sumsq (BN stats),
//   -> h stored row-major bf16 (via LDS transpose).
// Block: 256 thr (4 waves), BM=64 rows, BN=288 (256 h + 32 logit cols), BK=32.
// Wave wv owns h cols [wv*64, wv*64+64) and logit rows [wv*16, wv*16+16).
// ---------------------------------------------------------------------------
__global__ __launch_bounds__(256) void k_gemm(
    const float* __restrict__ feat, const float* __restrict__ b1,
    const float* __restrict__ bs, const int* __restrict__ segment,
    const u16* __restrict__ Wt, u16* __restrict__ h_out,
    float* __restrict__ sum_h, float* __restrict__ sumsq_h,
    float* __restrict__ scal)
{
    // 33792 B: K-loop uses As 4 KB + Bs 20 KB; epilogue reuses as 64x(264 u16) transpose buf
    __shared__ uint4 smem4[2112];
    uint4* const As4 = smem4;          // [4 kq][64 m] 16B slots, m XOR-swizzled by kq<<2
    uint4* const Bs4 = smem4 + 256;    // [4 kq][320 n] 16B slots

    const int t = threadIdx.x;
    const int lane = t & 63;
    const int wv = t >> 6;
    const int q = lane >> 4;          // k-quad for frag reads / row-quad of C layout
    const int i16 = lane & 15;
    const int row0 = blockIdx.x * 64;

    const f32x4 fz = {0.f, 0.f, 0.f, 0.f};
    f32x4 acc[4][4];                  // [row-tile][col-tile]
    f32x4 lacc[2];                    // logit col-tiles (cols 256+{0,16})
#pragma unroll
    for (int r = 0; r < 4; ++r)
#pragma unroll
        for (int c = 0; c < 4; ++c) acc[r][c] = fz;
    lacc[0] = fz; lacc[1] = fz;

    // feat staging: thread t -> row sm (0..63), k-group sq (0..3), 8 fp32
    const int sm = t >> 2;
    const int sq = t & 3;
    const float* fsrc = feat + (size_t)(row0 + sm) * 256 + sq * 8;
    const int As_wslot = sq * 64 + (sm ^ (sq << 2));

    float4 f0 = *(const float4*)(fsrc);
    float4 f1 = *(const float4*)(fsrc + 4);

#pragma unroll 1
    for (int kc = 0; kc < 8; ++kc) {
        const int k0 = kc * 32;
        // ---- stage feat tile (fp32 -> bf16, one ds_write_b128) ----
        {
            uint4 pk;
            pk.x = (u32)bf16rne(f0.x) | ((u32)bf16rne(f0.y) << 16);
            pk.y = (u32)bf16rne(f0.z) | ((u32)bf16rne(f0.w) << 16);
            pk.z = (u32)bf16rne(f1.x) | ((u32)bf16rne(f1.y) << 16);
            pk.w = (u32)bf16rne(f1.z) | ((u32)bf16rne(f1.w) << 16);
            As4[As_wslot] = pk;
        }
        // ---- stage Wt slab via global_load_lds width=16 (wave wv handles k-quad wv) ----
#pragma unroll
        for (int i = 0; i < 5; ++i) {
            const u16* src = Wt + (size_t)(i * 64 + lane) * 256 + k0 + wv * 8;
            u32* dst = (u32*)&Bs4[wv * 320 + i * 64];   // dest = base + lane*16
            __builtin_amdgcn_global_load_lds(
                (const __attribute__((address_space(1))) u32*)src,
                (__attribute__((address_space(3))) u32*)dst, 16, 0, 0);
        }
        __syncthreads();

        // prefetch next feat chunk under the MFMAs
        float4 fn0, fn1;
        if (kc < 7) {
            fn0 = *(const float4*)(fsrc + (kc + 1) * 32);
            fn1 = *(const float4*)(fsrc + (kc + 1) * 32 + 4);
        }

        // ---- fragments ----
        bf16x8 af[4], bfr[4], lbf[2], la;
#pragma unroll
        for (int r = 0; r < 4; ++r)
            af[r] = *(const bf16x8*)&As4[q * 64 + ((r * 16 + i16) ^ (q << 2))];
        la = *(const bf16x8*)&As4[q * 64 + ((wv * 16 + i16) ^ (q << 2))];
#pragma unroll
        for (int c = 0; c < 4; ++c)
            bfr[c] = *(const bf16x8*)&Bs4[q * 320 + wv * 64 + c * 16 + i16];
#pragma unroll
        for (int x = 0; x < 2; ++x)
            lbf[x] = *(const bf16x8*)&Bs4[q * 320 + 256 + x * 16 + i16];

#pragma unroll
        for (int r = 0; r < 4; ++r)
#pragma unroll
            for (int c = 0; c < 4; ++c)
                acc[r][c] = __builtin_amdgcn_mfma_f32_16x16x32_bf16(af[r], bfr[c], acc[r][c], 0, 0, 0);
#pragma unroll
        for (int x = 0; x < 2; ++x)
            lacc[x] = __builtin_amdgcn_mfma_f32_16x16x32_bf16(la, lbf[x], lacc[x], 0, 0, 0);
        __syncthreads();
        f0 = fn0; f1 = fn1;
    }

    // ---- epilogue ----
    float b1v[4];
#pragma unroll
    for (int c = 0; c < 4; ++c) b1v[c] = b1[wv * 64 + c * 16 + i16];
    float bsv0 = bs[i16];                                   // i16 < 16 < 20: always valid
    float bsv1 = (16 + i16 < KCLS) ? bs[16 + i16] : 0.f;

    // seg-head NLL for this wave's 16 logit rows. C layout: col=i16 (+16 for tile 1), row=q*4+j.
    float nllacc = 0.f, cntacc = 0.f;
#pragma unroll
    for (int j = 0; j < 4; ++j) {
        int rowr = row0 + wv * 16 + q * 4 + j;
        float l0 = lacc[0][j] + bsv0;                       // cols 0..15
        float l1raw = lacc[1][j] + bsv1;                    // cols 16..31 (only 16..19 real)
        float l1m = (i16 < 4) ? l1raw : -3.0e38f;
        float mx = fmaxf(l0, l1m);
#pragma unroll
        for (int d = 1; d < 16; d <<= 1) mx = fmaxf(mx, __shfl_xor(mx, d));
        float s = __expf(l0 - mx) + ((i16 < 4) ? __expf(l1raw - mx) : 0.f);
#pragma unroll
        for (int d = 1; d < 16; d <<= 1) s += __shfl_xor(s, d);
        int tg = segment[rowr];
        float v0 = __shfl(l0, (lane & 48) + (tg & 15));
        float v1 = __shfl(l1raw, (lane & 48) + ((tg - 16) & 15));
        float lt = (tg < 16) ? v0 : v1;
        if (i16 == 0 && tg >= 0) {                          // ignore_index = -1
            nllacc += __logf(s) + mx - lt;
            cntacc += 1.f;
        }
    }
#pragma unroll
    for (int d = 1; d < 64; d <<= 1) {
        nllacc += __shfl_xor(nllacc, d);
        cntacc += __shfl_xor(cntacc, d);
    }
    if (lane == 0) { atomicAdd(scal + 0, nllacc); atomicAdd(scal + 1, cntacc); }

    // per-channel sum / sumsq over this block's 64 rows
#pragma unroll
    for (int c = 0; c < 4; ++c) {
        float s1 = 0.f, s2 = 0.f;
#pragma unroll
        for (int r = 0; r < 4; ++r)
#pragma unroll
            for (int j = 0; j < 4; ++j) {
                float v = acc[r][c][j] + b1v[c];
                s1 += v; s2 = fmaf(v, v, s2);
            }
        s1 += __shfl_xor(s1, 16); s1 += __shfl_xor(s1, 32);
        s2 += __shfl_xor(s2, 16); s2 += __shfl_xor(s2, 32);
        if (q == 0) {
            atomicAdd(sum_h + wv * 64 + c * 16 + i16, s1);
            atomicAdd(sumsq_h + wv * 64 + c * 16 + i16, s2);
        }
    }

    // transpose h to row-major via LDS (rows padded to 264 u16 = 528 B to spread banks)
    u16* Ht = (u16*)smem4;
#pragma unroll
    for (int r = 0; r < 4; ++r)
#pragma unroll
        for (int c = 0; c < 4; ++c)
#pragma unroll
            for (int j = 0; j < 4; ++j) {
                float v = acc[r][c][j] + b1v[c];
                int rw = r * 16 + q * 4 + j;
                int cl = wv * 64 + c * 16 + i16;
                Ht[rw * 264 + cl] = bf16rne(v);
            }
    __syncthreads();
    // coalesced store: 64 rows x 512 B
#pragma unroll
    for (int i = 0; i < 8; ++i) {
        int chunk = i * 256 + t;          // 0..2047 of 16B
        int m = chunk >> 5;
        int off = (chunk & 31) * 16;
        uint4 v = *(const uint4*)((const char*)smem4 + m * 528 + off);
        *(uint4*)((char*)h_out + (size_t)(row0 + m) * 512 + off) = v;
    }
}

// ---------------------------------------------------------------------------
// kernel 2: fold BN into affine: hn = h*A + B
// ---------------------------------------------------------------------------
__global__ void k_stats(const float* __restrict__ gamma, const float* __restrict__ beta,
                        const float* __restrict__ sum_h, const float* __restrict__ sumsq_h,
                        float* __restrict__ Aarr, float* __restrict__ Barr) {
    int c = threadIdx.x;
    const float inv = 1.f / (float)NPTS;
    float mu = sum_h[c] * inv;
    float var = fmaxf(sumsq_h[c] * inv - mu * mu, 0.f);   // biased var (torch BN)
    float a = gamma[c] * rsqrtf(var + 1e-3f);
    Aarr[c] = a;
    Barr[c] = beta[c] - mu * a;
}

// ---------------------------------------------------------------------------
// kernel 3: per-row normalize+relu, bias_pred = hn@w2 + b2, masked L1 + cosine
// One wave per row (lane holds cols 4l..4l+3), 32 rows per wave.
// ---------------------------------------------------------------------------
__global__ __launch_bounds__(256) void k_loss(
    const u16* __restrict__ h, const float* __restrict__ Aarr, const float* __restrict__ Barr,
    const float* __restrict__ w2, const float* __restrict__ b2,
    const float* __restrict__ coord, const float* __restrict__ cent,
    const int* __restrict__ inst, float* __restrict__ scal)
{
    const int t = threadIdx.x;
    const int lane = t & 63;
    const int wv = t >> 6;
    const int rowbase = blockIdx.x * 128 + wv * 32;
    const int c4 = lane * 4;

    float4 Av = *(const float4*)(Aarr + c4);
    float4 Bv = *(const float4*)(Barr + c4);
    float4 wa = *(const float4*)(w2 + lane * 12);
    float4 wb = *(const float4*)(w2 + lane * 12 + 4);
    float4 wc = *(const float4*)(w2 + lane * 12 + 8);
    // w2 row (c4+j) components: j0:(wa.x,wa.y,wa.z) j1:(wa.w,wb.x,wb.y) j2:(wb.z,wb.w,wc.x) j3:(wc.y,wc.z,wc.w)
    float b2x = b2[0], b2y = b2[1], b2z = b2[2];

    float l1a = 0.f, cosa = 0.f, ma = 0.f;
    for (int rr = 0; rr < 32; ++rr) {
        int row = rowbase + rr;
        ushort4 u = *(const ushort4*)(h + (size_t)row * 256 + c4);
        float t0 = fmaxf(fmaf(bf2f(u.x), Av.x, Bv.x), 0.f);
        float t1 = fmaxf(fmaf(bf2f(u.y), Av.y, Bv.y), 0.f);
        float t2 = fmaxf(fmaf(bf2f(u.z), Av.z, Bv.z), 0.f);
        float t3 = fmaxf(fmaf(bf2f(u.w), Av.w, Bv.w), 0.f);
        float p0 = fmaf(t0, wa.x, fmaf(t1, wa.w, fmaf(t2, wb.z, t3 * wc.y)));
        float p1 = fmaf(t0, wa.y, fmaf(t1, wb.x, fmaf(t2, wb.w, t3 * wc.z)));
        float p2 = fmaf(t0, wa.z, fmaf(t1, wb.y, fmaf(t2, wc.x, t3 * wc.w)));
#pragma unroll
        for (int d = 1; d < 64; d <<= 1) {
            p0 += __shfl_xor(p0, d);
            p1 += __shfl_xor(p1, d);
            p2 += __shfl_xor(p2, d);
        }
        if (lane == 0) {
            float bpx = p0 + b2x, bpy = p1 + b2y, bpz = p2 + b2z;
            const float* cp = coord + (size_t)row * 3;
            const float* ip = cent + (size_t)row * 3;
            float gx = ip[0] - cp[0], gy = ip[1] - cp[1], gz = ip[2] - cp[2];
            float mk = (inst[row] != -1) ? 1.f : 0.f;
            float l1 = fabsf(bpx - gx) + fabsf(bpy - gy) + fabsf(bpz - gz);
            float np = sqrtf(fmaf(bpx, bpx, fmaf(bpy, bpy, bpz * bpz)));
            float ng = sqrtf(fmaf(gx, gx, fmaf(gy, gy, gz * gz)));
            float dp = fmaf(bpx, gx, fmaf(bpy, gy, bpz * gz));
            float cosv = -dp / ((np + 1e-8f) * (ng + 1e-8f));
            l1a = fmaf(l1, mk, l1a);
            cosa = fmaf(cosv, mk, cosa);
            ma += mk;
        }
    }
    if (lane == 0) {
        atomicAdd(scal + 2, l1a);
        atomicAdd(scal + 3, cosa);
        atomicAdd(scal + 4, ma);
    }
}

// ---------------------------------------------------------------------------
// kernel 4: final scalars
// ---------------------------------------------------------------------------
__global__ void k_final(const float* __restrict__ scal, float* __restrict__ out) {
    float seg = scal[0] / (scal[1] + 1e-8f);
    float l1 = scal[2] / (scal[4] + 1e-8f);
    float cs = scal[3] / (scal[4] + 1e-8f);
    out[0] = seg + l1 + cs;
    out[1] = seg;
    out[2] = l1;
    out[3] = cs;
}

extern "C" void kernel_launch(void* const* d_in, const int* in_sizes, int n_in,
                              void* d_out, int out_size, void* d_ws, size_t ws_size,
                              hipStream_t stream) {
    const float* feat   = (const float*)d_in[0];
    const float* coord  = (const float*)d_in[1];
    const float* cent   = (const float*)d_in[2];
    const int* segment  = (const int*)d_in[3];
    const int* inst     = (const int*)d_in[4];
    const float* w1     = (const float*)d_in[5];
    const float* b1     = (const float*)d_in[6];
    const float* gamma  = (const float*)d_in[7];
    const float* beta   = (const float*)d_in[8];
    const float* w2     = (const float*)d_in[9];
    const float* b2     = (const float*)d_in[10];
    const float* wsm    = (const float*)d_in[11];
    const float* bs     = (const float*)d_in[12];
    float* out = (float*)d_out;

    char* wsb = (char*)d_ws;
    u16* h_ws   = (u16*)wsb;
    u16* Wt     = (u16*)(wsb + OFF_WT);
    float* stats = (float*)(wsb + OFF_STAT);
    float* sum_h   = stats;
    float* sumsq_h = stats + 256;
    float* Aarr    = stats + 512;
    float* Barr    = stats + 768;
    float* scal    = stats + 1024;

    if (ws_size < WS_NEED)
        fprintf(stderr, "kernel_launch: ws_size=%zu < needed %zu — WILL CORRUPT\n",
                ws_size, (size_t)WS_NEED);

    hipMemsetAsync(stats, 0, 4160, stream);
    k_prep<<<320, 256, 0, stream>>>(w1, wsm, Wt);
    k_gemm<<<4096, 256, 0, stream>>>(feat, b1, bs, segment, Wt, h_ws, sum_h, sumsq_h, scal);
    k_stats<<<1, 256, 0, stream>>>(gamma, beta, sum_h, sumsq_h, Aarr, Barr);
    k_loss<<<2048, 256, 0, stream>>>(h_ws, Aarr, Barr, w2, b2, coord, cent, inst, scal);
    k_final<<<1, 1, 0, stream>>>(scal, out);
}

// Round 2
// 550.140 us; speedup vs baseline: 2.0279x; 2.0279x over previous
//
#include <hip/hip_runtime.h>
#include <cstdio>
#include <cstdint>

typedef unsigned int u32;
typedef unsigned short u16;
typedef short bf16x8 __attribute__((ext_vector_type(8)));   // 8 bf16 = 4 VGPRs (MFMA A/B operand)
typedef float f32x4 __attribute__((ext_vector_type(4)));    // MFMA C/D operand

#define NPTS 262144
#define CDIM 256
#define KCLS 20
#define NBLK 4096          // k_gemm blocks (BM=64)
#define NSLOT 256          // BN/NLL aggregation slots
#define LSLOT 64           // loss aggregation slots

// ---- workspace layout (bytes) ----
// [0, 134217728)       : h bf16 [N][256] row-major
// + 163840             : Wt bf16 [320][256]
// + 524288             : aggBN  [256][512] f32 (sum_h[256] | sumsq_h[256] per slot)
// + 2048               : aggNLL [256][2]  f32 (nll, cnt)
// + 1024               : aggL   [64][4]   f32 (l1, cos, mask, pad)
// + 2048               : Aarr[256], Barr[256]
#define OFF_WT    ((size_t)134217728)
#define OFF_AGGBN (OFF_WT + (size_t)163840)
#define OFF_AGGNL (OFF_AGGBN + (size_t)524288)
#define OFF_AGGL  (OFF_AGGNL + (size_t)2048)
#define OFF_AB    (OFF_AGGL + (size_t)1024)
#define WS_NEED   (OFF_AB + (size_t)2048)
#define MEMSET_OFF OFF_AGGBN
#define MEMSET_LEN ((size_t)(524288 + 2048 + 1024))

__device__ __forceinline__ u16 bf16rne(float x) {
    u32 u = __float_as_uint(x);
    u32 r = u + 0x7FFFu + ((u >> 16) & 1u);   // round-to-nearest-even
    return (u16)(r >> 16);
}
__device__ __forceinline__ float bf2f(u16 b) {
    return __uint_as_float(((u32)b) << 16);
}

// ---------------------------------------------------------------------------
// kernel 0: build Wt[320][256] bf16 = transposed [w1 | ws | zero-pad]
// grid 256 x 320thr: read side (cold HBM) coalesced; scattered writes land in L2.
// ---------------------------------------------------------------------------
__global__ void k_prep(const float* __restrict__ w1, const float* __restrict__ wsm,
                       u16* __restrict__ Wt) {
    int k = blockIdx.x;      // 0..255
    int n = threadIdx.x;     // 0..319
    float v = 0.f;
    if (n < 256) v = w1[k * 256 + n];
    else if (n < 256 + KCLS) v = wsm[k * KCLS + (n - 256)];
    Wt[n * 256 + k] = bf16rne(v);
}

// ---------------------------------------------------------------------------
// kernel 1: h = feat @ w1 (+b1) via bf16 MFMA; fused logits = feat @ ws (+bs)
//   -> seg NLL partials, per-channel sum/sumsq partials (256-slot fan-out),
//   -> h stored row-major bf16 (LDS transpose).
// ---------------------------------------------------------------------------
__global__ __launch_bounds__(256) void k_gemm(
    const float* __restrict__ feat, const float* __restrict__ b1,
    const float* __restrict__ bs, const int* __restrict__ segment,
    const u16* __restrict__ Wt, u16* __restrict__ h_out,
    float* __restrict__ aggBN, float* __restrict__ aggNLL)
{
    // 33792 B: K-loop uses As 4 KB + Bs 20 KB; epilogue reuses as 64x(264 u16) transpose buf
    __shared__ uint4 smem4[2112];
    uint4* const As4 = smem4;          // [4 kq][64 m] 16B slots, m XOR-swizzled by kq<<2
    uint4* const Bs4 = smem4 + 256;    // [4 kq][320 n] 16B slots

    const int t = threadIdx.x;
    const int lane = t & 63;
    const int wv = t >> 6;
    const int q = lane >> 4;          // k-quad for frag reads / row-quad of C layout
    const int i16 = lane & 15;
    const int row0 = blockIdx.x * 64;
    const int slot = blockIdx.x & (NSLOT - 1);

    const f32x4 fz = {0.f, 0.f, 0.f, 0.f};
    f32x4 acc[4][4];                  // [row-tile][col-tile]
    f32x4 lacc[2];                    // logit col-tiles (cols 256+{0,16})
#pragma unroll
    for (int r = 0; r < 4; ++r)
#pragma unroll
        for (int c = 0; c < 4; ++c) acc[r][c] = fz;
    lacc[0] = fz; lacc[1] = fz;

    // feat staging: thread t -> row sm (0..63), k-group sq (0..3), 8 fp32
    const int sm = t >> 2;
    const int sq = t & 3;
    const float* fsrc = feat + (size_t)(row0 + sm) * 256 + sq * 8;
    const int As_wslot = sq * 64 + (sm ^ (sq << 2));

    float4 f0 = *(const float4*)(fsrc);
    float4 f1 = *(const float4*)(fsrc + 4);

#pragma unroll 1
    for (int kc = 0; kc < 8; ++kc) {
        const int k0 = kc * 32;
        // ---- stage feat tile (fp32 -> bf16, one ds_write_b128) ----
        {
            uint4 pk;
            pk.x = (u32)bf16rne(f0.x) | ((u32)bf16rne(f0.y) << 16);
            pk.y = (u32)bf16rne(f0.z) | ((u32)bf16rne(f0.w) << 16);
            pk.z = (u32)bf16rne(f1.x) | ((u32)bf16rne(f1.y) << 16);
            pk.w = (u32)bf16rne(f1.z) | ((u32)bf16rne(f1.w) << 16);
            As4[As_wslot] = pk;
        }
        // ---- stage Wt slab via global_load_lds width=16 (wave wv handles k-quad wv) ----
#pragma unroll
        for (int i = 0; i < 5; ++i) {
            const u16* src = Wt + (size_t)(i * 64 + lane) * 256 + k0 + wv * 8;
            u32* dst = (u32*)&Bs4[wv * 320 + i * 64];   // dest = base + lane*16
            __builtin_amdgcn_global_load_lds(
                (const __attribute__((address_space(1))) u32*)src,
                (__attribute__((address_space(3))) u32*)dst, 16, 0, 0);
        }
        __syncthreads();

        // prefetch next feat chunk under the MFMAs
        float4 fn0, fn1;
        if (kc < 7) {
            fn0 = *(const float4*)(fsrc + (kc + 1) * 32);
            fn1 = *(const float4*)(fsrc + (kc + 1) * 32 + 4);
        }

        // ---- fragments ----
        bf16x8 af[4], bfr[4], lbf[2], la;
#pragma unroll
        for (int r = 0; r < 4; ++r)
            af[r] = *(const bf16x8*)&As4[q * 64 + ((r * 16 + i16) ^ (q << 2))];
        la = *(const bf16x8*)&As4[q * 64 + ((wv * 16 + i16) ^ (q << 2))];
#pragma unroll
        for (int c = 0; c < 4; ++c)
            bfr[c] = *(const bf16x8*)&Bs4[q * 320 + wv * 64 + c * 16 + i16];
#pragma unroll
        for (int x = 0; x < 2; ++x)
            lbf[x] = *(const bf16x8*)&Bs4[q * 320 + 256 + x * 16 + i16];

#pragma unroll
        for (int r = 0; r < 4; ++r)
#pragma unroll
            for (int c = 0; c < 4; ++c)
                acc[r][c] = __builtin_amdgcn_mfma_f32_16x16x32_bf16(af[r], bfr[c], acc[r][c], 0, 0, 0);
#pragma unroll
        for (int x = 0; x < 2; ++x)
            lacc[x] = __builtin_amdgcn_mfma_f32_16x16x32_bf16(la, lbf[x], lacc[x], 0, 0, 0);
        __syncthreads();
        f0 = fn0; f1 = fn1;
    }

    // ---- epilogue ----
    float b1v[4];
#pragma unroll
    for (int c = 0; c < 4; ++c) b1v[c] = b1[wv * 64 + c * 16 + i16];
    float bsv0 = bs[i16];                                   // i16 < 16 < 20: always valid
    float bsv1 = (16 + i16 < KCLS) ? bs[16 + i16] : 0.f;

    // seg-head NLL for this wave's 16 logit rows. C layout: col=i16 (+16 for tile 1), row=q*4+j.
    float nllacc = 0.f, cntacc = 0.f;
#pragma unroll
    for (int j = 0; j < 4; ++j) {
        int rowr = row0 + wv * 16 + q * 4 + j;
        float l0 = lacc[0][j] + bsv0;                       // cols 0..15
        float l1raw = lacc[1][j] + bsv1;                    // cols 16..31 (only 16..19 real)
        float l1m = (i16 < 4) ? l1raw : -3.0e38f;
        float mx = fmaxf(l0, l1m);
#pragma unroll
        for (int d = 1; d < 16; d <<= 1) mx = fmaxf(mx, __shfl_xor(mx, d));
        float s = __expf(l0 - mx) + ((i16 < 4) ? __expf(l1raw - mx) : 0.f);
#pragma unroll
        for (int d = 1; d < 16; d <<= 1) s += __shfl_xor(s, d);
        int tg = segment[rowr];
        float v0 = __shfl(l0, (lane & 48) + (tg & 15));
        float v1 = __shfl(l1raw, (lane & 48) + ((tg - 16) & 15));
        float lt = (tg < 16) ? v0 : v1;
        if (i16 == 0 && tg >= 0) {                          // ignore_index = -1
            nllacc += __logf(s) + mx - lt;
            cntacc += 1.f;
        }
    }
#pragma unroll
    for (int d = 1; d < 64; d <<= 1) {
        nllacc += __shfl_xor(nllacc, d);
        cntacc += __shfl_xor(cntacc, d);
    }
    if (t == 0) { atomicAdd(aggNLL + slot * 2, 0.f); }      // keep slot line warm (no-op)
    if (lane == 0) {
        atomicAdd(aggNLL + slot * 2 + 0, nllacc);
        atomicAdd(aggNLL + slot * 2 + 1, cntacc);
    }

    // per-channel sum / sumsq over this block's 64 rows -> 256-slot fan-out
#pragma unroll
    for (int c = 0; c < 4; ++c) {
        float s1 = 0.f, s2 = 0.f;
#pragma unroll
        for (int r = 0; r < 4; ++r)
#pragma unroll
            for (int j = 0; j < 4; ++j) {
                float v = acc[r][c][j] + b1v[c];
                s1 += v; s2 = fmaf(v, v, s2);
            }
        s1 += __shfl_xor(s1, 16); s1 += __shfl_xor(s1, 32);
        s2 += __shfl_xor(s2, 16); s2 += __shfl_xor(s2, 32);
        if (q == 0) {
            int ch = wv * 64 + c * 16 + i16;
            atomicAdd(aggBN + slot * 512 + ch, s1);
            atomicAdd(aggBN + slot * 512 + 256 + ch, s2);
        }
    }

    // transpose h to row-major via LDS (rows padded to 264 u16 = 528 B to spread banks)
    u16* Ht = (u16*)smem4;
#pragma unroll
    for (int r = 0; r < 4; ++r)
#pragma unroll
        for (int c = 0; c < 4; ++c)
#pragma unroll
            for (int j = 0; j < 4; ++j) {
                float v = acc[r][c][j] + b1v[c];
                int rw = r * 16 + q * 4 + j;
                int cl = wv * 64 + c * 16 + i16;
                Ht[rw * 264 + cl] = bf16rne(v);
            }
    __syncthreads();
    // coalesced store: 64 rows x 512 B
#pragma unroll
    for (int i = 0; i < 8; ++i) {
        int chunk = i * 256 + t;          // 0..2047 of 16B
        int m = chunk >> 5;
        int off = (chunk & 31) * 16;
        uint4 v = *(const uint4*)((const char*)smem4 + m * 528 + off);
        *(uint4*)((char*)h_out + (size_t)(row0 + m) * 512 + off) = v;
    }
}

// ---------------------------------------------------------------------------
// kernel 2: reduce BN slot partials, fold BN into affine: hn = h*A + B
// ---------------------------------------------------------------------------
__global__ void k_reduce(const float* __restrict__ gamma, const float* __restrict__ beta,
                         const float* __restrict__ aggBN,
                         float* __restrict__ Aarr, float* __restrict__ Barr) {
    int c = threadIdx.x;   // 0..255
    float s1 = 0.f, s2 = 0.f;
    for (int s = 0; s < NSLOT; ++s) {
        s1 += aggBN[s * 512 + c];
        s2 += aggBN[s * 512 + 256 + c];
    }
    const float inv = 1.f / (float)NPTS;
    float mu = s1 * inv;
    float var = fmaxf(s2 * inv - mu * mu, 0.f);   // biased var (torch BN)
    float a = gamma[c] * rsqrtf(var + 1e-3f);
    Aarr[c] = a;
    Barr[c] = beta[c] - mu * a;
}

// ---------------------------------------------------------------------------
// kernel 3: per-row normalize+relu, bias_pred = hn@w2 + b2, masked L1 + cosine
// One wave per row (lane holds cols 4l..4l+3), 32 rows per wave.
// Block-level LDS combine -> 3 atomics/block over 64 slots.
// ---------------------------------------------------------------------------
__global__ __launch_bounds__(256) void k_loss(
    const u16* __restrict__ h, const float* __restrict__ Aarr, const float* __restrict__ Barr,
    const float* __restrict__ w2, const float* __restrict__ b2,
    const float* __restrict__ coord, const float* __restrict__ cent,
    const int* __restrict__ inst, float* __restrict__ aggL)
{
    __shared__ float red[12];
    const int t = threadIdx.x;
    const int lane = t & 63;
    const int wv = t >> 6;
    const int rowbase = blockIdx.x * 128 + wv * 32;
    const int c4 = lane * 4;

    float4 Av = *(const float4*)(Aarr + c4);
    float4 Bv = *(const float4*)(Barr + c4);
    float4 wa = *(const float4*)(w2 + lane * 12);
    float4 wb = *(const float4*)(w2 + lane * 12 + 4);
    float4 wc = *(const float4*)(w2 + lane * 12 + 8);
    // w2 row (c4+j) components: j0:(wa.x,wa.y,wa.z) j1:(wa.w,wb.x,wb.y) j2:(wb.z,wb.w,wc.x) j3:(wc.y,wc.z,wc.w)
    float b2x = b2[0], b2y = b2[1], b2z = b2[2];

    float l1a = 0.f, cosa = 0.f, ma = 0.f;
    for (int rr = 0; rr < 32; ++rr) {
        int row = rowbase + rr;
        ushort4 u = *(const ushort4*)(h + (size_t)row * 256 + c4);
        float t0 = fmaxf(fmaf(bf2f(u.x), Av.x, Bv.x), 0.f);
        float t1 = fmaxf(fmaf(bf2f(u.y), Av.y, Bv.y), 0.f);
        float t2 = fmaxf(fmaf(bf2f(u.z), Av.z, Bv.z), 0.f);
        float t3 = fmaxf(fmaf(bf2f(u.w), Av.w, Bv.w), 0.f);
        float p0 = fmaf(t0, wa.x, fmaf(t1, wa.w, fmaf(t2, wb.z, t3 * wc.y)));
        float p1 = fmaf(t0, wa.y, fmaf(t1, wb.x, fmaf(t2, wb.w, t3 * wc.z)));
        float p2 = fmaf(t0, wa.z, fmaf(t1, wb.y, fmaf(t2, wc.x, t3 * wc.w)));
#pragma unroll
        for (int d = 1; d < 64; d <<= 1) {
            p0 += __shfl_xor(p0, d);
            p1 += __shfl_xor(p1, d);
            p2 += __shfl_xor(p2, d);
        }
        if (lane == 0) {
            float bpx = p0 + b2x, bpy = p1 + b2y, bpz = p2 + b2z;
            const float* cp = coord + (size_t)row * 3;
            const float* ip = cent + (size_t)row * 3;
            float gx = ip[0] - cp[0], gy = ip[1] - cp[1], gz = ip[2] - cp[2];
            float mk = (inst[row] != -1) ? 1.f : 0.f;
            float l1 = fabsf(bpx - gx) + fabsf(bpy - gy) + fabsf(bpz - gz);
            float np = sqrtf(fmaf(bpx, bpx, fmaf(bpy, bpy, bpz * bpz)));
            float ng = sqrtf(fmaf(gx, gx, fmaf(gy, gy, gz * gz)));
            float dp = fmaf(bpx, gx, fmaf(bpy, gy, bpz * gz));
            float cosv = -dp / ((np + 1e-8f) * (ng + 1e-8f));
            l1a = fmaf(l1, mk, l1a);
            cosa = fmaf(cosv, mk, cosa);
            ma += mk;
        }
    }
    if (lane == 0) { red[wv] = l1a; red[4 + wv] = cosa; red[8 + wv] = ma; }
    __syncthreads();
    if (t == 0) {
        int slot = blockIdx.x & (LSLOT - 1);
        atomicAdd(aggL + slot * 4 + 0, red[0] + red[1] + red[2] + red[3]);
        atomicAdd(aggL + slot * 4 + 1, red[4] + red[5] + red[6] + red[7]);
        atomicAdd(aggL + slot * 4 + 2, red[8] + red[9] + red[10] + red[11]);
    }
}

// ---------------------------------------------------------------------------
// kernel 4: final scalars — reduce NLL + loss slots, emit 4 outputs (1 wave)
// ---------------------------------------------------------------------------
__global__ void k_final(const float* __restrict__ aggNLL, const float* __restrict__ aggL,
                        float* __restrict__ out) {
    int lane = threadIdx.x;   // 0..63
    float nll = 0.f, cnt = 0.f;
#pragma unroll
    for (int i = 0; i < 4; ++i) {
        int s = lane + i * 64;
        nll += aggNLL[s * 2 + 0];
        cnt += aggNLL[s * 2 + 1];
    }
    float l1 = aggL[lane * 4 + 0];
    float cs = aggL[lane * 4 + 1];
    float mk = aggL[lane * 4 + 2];
#pragma unroll
    for (int d = 1; d < 64; d <<= 1) {
        nll += __shfl_xor(nll, d);
        cnt += __shfl_xor(cnt, d);
        l1 += __shfl_xor(l1, d);
        cs += __shfl_xor(cs, d);
        mk += __shfl_xor(mk, d);
    }
    if (lane == 0) {
        float seg = nll / (cnt + 1e-8f);
        float l1l = l1 / (mk + 1e-8f);
        float csl = cs / (mk + 1e-8f);
        out[0] = seg + l1l + csl;
        out[1] = seg;
        out[2] = l1l;
        out[3] = csl;
    }
}

extern "C" void kernel_launch(void* const* d_in, const int* in_sizes, int n_in,
                              void* d_out, int out_size, void* d_ws, size_t ws_size,
                              hipStream_t stream) {
    const float* feat   = (const float*)d_in[0];
    const float* coord  = (const float*)d_in[1];
    const float* cent   = (const float*)d_in[2];
    const int* segment  = (const int*)d_in[3];
    const int* inst     = (const int*)d_in[4];
    const float* w1     = (const float*)d_in[5];
    const float* b1     = (const float*)d_in[6];
    const float* gamma  = (const float*)d_in[7];
    const float* beta   = (const float*)d_in[8];
    const float* w2     = (const float*)d_in[9];
    const float* b2     = (const float*)d_in[10];
    const float* wsm    = (const float*)d_in[11];
    const float* bs     = (const float*)d_in[12];
    float* out = (float*)d_out;

    char* wsb = (char*)d_ws;
    u16* h_ws    = (u16*)wsb;
    u16* Wt      = (u16*)(wsb + OFF_WT);
    float* aggBN = (float*)(wsb + OFF_AGGBN);
    float* aggNL = (float*)(wsb + OFF_AGGNL);
    float* aggL  = (float*)(wsb + OFF_AGGL);
    float* Aarr  = (float*)(wsb + OFF_AB);
    float* Barr  = Aarr + 256;

    if (ws_size < WS_NEED)
        fprintf(stderr, "kernel_launch: ws_size=%zu < needed %zu — WILL CORRUPT\n",
                ws_size, (size_t)WS_NEED);

    hipMemsetAsync(wsb + MEMSET_OFF, 0, MEMSET_LEN, stream);
    k_prep<<<256, 320, 0, stream>>>(w1, wsm, Wt);
    k_gemm<<<NBLK, 256, 0, stream>>>(feat, b1, bs, segment, Wt, h_ws, aggBN, aggNL);
    k_reduce<<<1, 256, 0, stream>>>(gamma, beta, aggBN, Aarr, Barr);
    k_loss<<<2048, 256, 0, stream>>>(h_ws, Aarr, Barr, w2, b2, coord, cent, inst, aggL);
    k_final<<<1, 64, 0, stream>>>(aggNL, aggL, out);
}